// Round 10
// baseline (296.282 us; speedup 1.0000x reference)
//
#include <hip/hip_runtime.h>

#define BATCH 128
#define SEQ   1024
#define DIM   128
#define NCAP  32
#define DCAPS 16
#define KTOT  512
#define EPS_  1e-7f
#define RCH   8
#define RROWS 128

// ws layout (float offsets)
#define OFF_SPART 0                                  // [B][RCH][DIM] f32
#define OFF_WT    (OFF_SPART + BATCH*RCH*DIM)        // [KTOT][DIM] f32
#define OFF_UBF   (OFF_WT + KTOT*DIM)                // [B][NCAP][DIM] bf16
#define OFF_VP    (OFF_UBF + BATCH*NCAP*DIM/2)       // [B][RCH][NCAP][DIM] bf16
#define OFF_XROW  (OFF_VP + BATCH*RCH*NCAP*DIM/2)    // [B][SEQ][DIM] bf16
#define OFF_CNT   (OFF_XROW + BATCH*SEQ*DIM/2)       // [2*B] int32 tail counters
// end ≈ 43.8 MB

typedef __attribute__((ext_vector_type(8))) short short8v;   // 8 bf16
typedef __attribute__((ext_vector_type(4))) float f32x4;
typedef unsigned short ushort_t;

// subtiled LDS layout for the X tile: subtile (r4,d16) holds rows r4*4..+3,
// cols d16*16..+15, row-major [4][16] bf16 (32B row stride).
// stride 176 = 128B payload + 48B gap: disjoint, staging stores and
// phase-A ds_read_b128 are bank-balanced at the throughput floor.
#define SUBOFF(r4, d16) (((r4)*8 + (d16))*176)
#define CTOFF 45056      // > max subtile end (255*176+128 = 45008), 128-aligned
#define SMEMSZ (CTOFF + 8192)

__device__ __forceinline__ unsigned f2bf(float f) {
  unsigned u = __float_as_uint(f);
  u += 0x7fffu + ((u >> 16) & 1u);    // RNE
  return u >> 16;
}
__device__ __forceinline__ float bf2f(ushort_t v) {
  return __uint_as_float(((unsigned)v) << 16);
}
__device__ __forceinline__ uint4 pack8(float4 a, float4 b) {
  uint4 r;
  r.x = f2bf(a.x) | (f2bf(a.y) << 16);
  r.y = f2bf(a.z) | (f2bf(a.w) << 16);
  r.z = f2bf(b.x) | (f2bf(b.y) << 16);
  r.w = f2bf(b.z) | (f2bf(b.w) << 16);
  return r;
}

// ---------- kernel 1: colsum partials + WT transpose + xrow bf16 image ----------
__global__ __launch_bounds__(256)
void k_pre(const float* __restrict__ x, const float* __restrict__ w,
           float* __restrict__ ws) {
  int t = threadIdx.x;
  __shared__ __align__(16) char smem[33792];

  if (blockIdx.y == BATCH) {              // 8 blocks: LDS-tiled W transpose
    if (blockIdx.x == 0 && t < 2 * BATCH) // zero tail counters each launch
      ((int*)(ws + OFF_CNT))[t] = 0;
    float* wl = (float*)smem;             // [128][66] padded tile
    int k0 = blockIdx.x * 64;
    for (int it = 0; it < 32; ++it) {
      int f = it * 256 + t;
      int kk = f & 63, d = f >> 6;
      wl[d * 66 + kk] = w[d * KTOT + k0 + kk];
    }
    __syncthreads();
    float* wt = ws + OFF_WT;
    for (int it = 0; it < 32; ++it) {
      int f = it * 256 + t;
      int d = f & 127, kk = f >> 7;
      wt[(size_t)(k0 + kk) * DIM + d] = wl[d * 66 + kk];
    }
    return;
  }
  int b = blockIdx.y, ch = blockIdx.x;
  float4* red0 = (float4*)smem;            // [16][16]
  float4* red1 = (float4*)(smem + 4096);   // [16][16]

  const float4* X4 = (const float4*)(x + ((size_t)b * SEQ + (size_t)ch * RROWS) * DIM);
  ushort_t* xrow = (ushort_t*)(ws + OFF_XROW) + ((size_t)b * SEQ + (size_t)ch * RROWS) * DIM;

  int seg = t & 15, grp = t >> 4;
  float4 a0 = make_float4(0.f,0.f,0.f,0.f), a1 = make_float4(0.f,0.f,0.f,0.f);
  for (int it = 0; it < 8; ++it) {
    int r = it * 16 + grp;
    float4 v0 = X4[(size_t)r * 32 + seg * 2];
    float4 v1 = X4[(size_t)r * 32 + seg * 2 + 1];
    a0.x += v0.x; a0.y += v0.y; a0.z += v0.z; a0.w += v0.w;
    a1.x += v1.x; a1.y += v1.y; a1.z += v1.z; a1.w += v1.w;
    *(uint4*)(xrow + (size_t)r * DIM + seg * 8) = pack8(v0, v1);
  }
  red0[grp * 16 + seg] = a0;
  red1[grp * 16 + seg] = a1;
  __syncthreads();

  if (t < 128) {
    int sg = t >> 3, e = t & 7;
    float s = 0.f;
    for (int g = 0; g < 16; ++g) {
      const float* p0 = (const float*)&red0[g * 16 + sg];
      const float* p1 = (const float*)&red1[g * 16 + sg];
      s += (e < 4) ? p0[e] : p1[e - 4];
    }
    ws[OFF_SPART + ((size_t)b * RCH + ch) * DIM + t] = s;
  }
}

// ---------- kernel 2: squash + u0(bf16) from colsum ----------
__global__ __launch_bounds__(128)
void k_ou0(float* __restrict__ ws) {
  int b = blockIdx.y, bx = blockIdx.x, t = threadIdx.x;
  int k = bx * 128 + t;
  __shared__ float vin[DIM];
  __shared__ float osh[128];

  const float* sp = ws + OFF_SPART + (size_t)b * RCH * DIM;
  float s = 0.f;
  for (int c = 0; c < RCH; ++c) s += sp[c * DIM + t];
  vin[t] = s * (1.0f / 32.0f);
  __syncthreads();

  const float4* vr = (const float4*)vin;
  const float4* wtr = (const float4*)(ws + OFF_WT + (size_t)k * DIM);
  float p = 0.f;
  #pragma unroll 8
  for (int i = 0; i < 32; ++i) {
    float4 wv = wtr[i], vv = vr[i];
    p += wv.x * vv.x + wv.y * vv.y + wv.z * vv.z + wv.w * vv.w;
  }

  float sq = p * p;
  sq += __shfl_xor(sq, 1, 16);
  sq += __shfl_xor(sq, 2, 16);
  sq += __shfl_xor(sq, 4, 16);
  sq += __shfl_xor(sq, 8, 16);
  sq += EPS_;
  float scale = sqrtf(sq) / (0.5f + sq);
  float o = scale * p;

  osh[t] = o;
  __syncthreads();

  const float* wt = ws + OFF_WT;
  ushort_t* ubf = (ushort_t*)(ws + OFF_UBF) + (size_t)b * NCAP * DIM;
  for (int j = 0; j < 8; ++j) {
    int n = bx * 8 + j;
    float a = 0.f;
    #pragma unroll
    for (int dc = 0; dc < DCAPS; ++dc)
      a += wt[(size_t)(n * DCAPS + dc) * DIM + t] * osh[j * DCAPS + dc];
    ubf[(size_t)n * DIM + t] = (ushort_t)f2bf(a);
  }
}

// ---------- kernel 3: MFMA routing pass + fused per-batch tail ----------
// PASS 1: tail computes u1 (bf16). PASS 2: tail writes final output (f32).
template<int PASS>
__global__ __launch_bounds__(256)
void k_route(float* __restrict__ ws_c, float* __restrict__ outp) {
  __shared__ __align__(16) char smem[SMEMSZ];

  int b = blockIdx.y, ch = blockIdx.x, t = threadIdx.x;
  int wv = t >> 6;
  int l  = t & 63;
  int q  = l >> 4;
  int lr = l & 15;

  const ushort_t* ubf  = (const ushort_t*)(ws_c + OFF_UBF) + (size_t)b * NCAP * DIM;
  const ushort_t* xrow = (const ushort_t*)(ws_c + OFF_XROW) + ((size_t)b * SEQ + (size_t)ch * RROWS) * DIM;

  // ---- stage tile: global row-major -> LDS subtiled ----
  #pragma unroll
  for (int it = 0; it < 8; ++it) {
    int f = it * 256 + t;
    int r = f >> 4, d0 = (f & 15) * 8;
    uint4 v = *(const uint4*)(xrow + (size_t)r * DIM + d0);
    *(uint4*)(smem + SUBOFF(r >> 2, d0 >> 4) + (r & 3) * 32 + ((d0 & 15) << 1)) = v;
  }

  short8v ufr[2][4];
  #pragma unroll
  for (int nt = 0; nt < 2; ++nt)
    #pragma unroll
    for (int kk = 0; kk < 4; ++kk)
      ufr[nt][kk] = *(const short8v*)(ubf + (size_t)(nt * 16 + lr) * DIM + kk * 32 + q * 8);

  __syncthreads();

  // ---- phase A ----
  f32x4 acc[2][2];
  #pragma unroll
  for (int rt = 0; rt < 2; ++rt)
    #pragma unroll
    for (int nt = 0; nt < 2; ++nt)
      acc[rt][nt] = (f32x4){0.f, 0.f, 0.f, 0.f};

  #pragma unroll
  for (int kk = 0; kk < 4; ++kk) {
    #pragma unroll
    for (int rt = 0; rt < 2; ++rt) {
      int r = wv * 32 + rt * 16 + lr;
      short8v xf = *(const short8v*)(smem + SUBOFF(r >> 2, 2 * kk + (q >> 1))
                                     + (r & 3) * 32 + (q & 1) * 16);
      #pragma unroll
      for (int nt = 0; nt < 2; ++nt)
        acc[rt][nt] = __builtin_amdgcn_mfma_f32_16x16x32_bf16(
            ufr[nt][kk], xf, acc[rt][nt], 0, 0, 0);
    }
  }

  // ---- hoisted phase-C column gathers ----
  union { short8v v; ushort_t s[8]; } ax0[4], ax1[4];
  #pragma unroll
  for (int kk = 0; kk < 4; ++kk) {
    #pragma unroll
    for (int e = 0; e < 8; ++e) {
      int r4 = kk * 8 + q * 2 + (e >> 2);
      int boff = (e & 3) * 32 + lr * 2;
      ax0[kk].s[e] = *(const ushort_t*)(smem + SUBOFF(r4, wv * 2    ) + boff);
      ax1[kk].s[e] = *(const ushort_t*)(smem + SUBOFF(r4, wv * 2 + 1) + boff);
    }
  }

  // ---- softmax over n; c -> ct ----
  #pragma unroll
  for (int rt = 0; rt < 2; ++rt) {
    float v[8];
    #pragma unroll
    for (int nt = 0; nt < 2; ++nt)
      #pragma unroll
      for (int j = 0; j < 4; ++j) v[nt * 4 + j] = acc[rt][nt][j];
    float m = v[0];
    #pragma unroll
    for (int i = 1; i < 8; ++i) m = fmaxf(m, v[i]);
    m = fmaxf(m, __shfl_xor(m, 16));
    m = fmaxf(m, __shfl_xor(m, 32));
    float e[8], s = 0.f;
    #pragma unroll
    for (int i = 0; i < 8; ++i) { e[i] = __expf(v[i] - m); s += e[i]; }
    s += __shfl_xor(s, 16);
    s += __shfl_xor(s, 32);
    float inv = 1.0f / s;
    int r = wv * 32 + rt * 16 + lr;
    int rs = r >> 3, rb = (r & 7) * 2;
    #pragma unroll
    for (int nt = 0; nt < 2; ++nt)
      #pragma unroll
      for (int j = 0; j < 4; ++j) {
        int n = nt * 16 + q * 4 + j;
        *(ushort_t*)(smem + CTOFF + n * 256 + ((rs ^ (n & 15)) << 4) + rb) =
            (ushort_t)f2bf(e[nt * 4 + j] * inv);
      }
  }

  __syncthreads();

  // ---- phase C ----
  short8v bc[2][4];
  #pragma unroll
  for (int nt = 0; nt < 2; ++nt) {
    int n2 = nt * 16 + lr;
    #pragma unroll
    for (int kk = 0; kk < 4; ++kk)
      bc[nt][kk] = *(const short8v*)(smem + CTOFF + n2 * 256 + (((4 * kk + q) ^ (n2 & 15)) << 4));
  }

  f32x4 vac[2][2];
  #pragma unroll
  for (int dt = 0; dt < 2; ++dt)
    #pragma unroll
    for (int nt = 0; nt < 2; ++nt)
      vac[dt][nt] = (f32x4){0.f, 0.f, 0.f, 0.f};

  #pragma unroll
  for (int kk = 0; kk < 4; ++kk) {
    #pragma unroll
    for (int nt = 0; nt < 2; ++nt) {
      vac[0][nt] = __builtin_amdgcn_mfma_f32_16x16x32_bf16(ax0[kk].v, bc[nt][kk], vac[0][nt], 0, 0, 0);
      vac[1][nt] = __builtin_amdgcn_mfma_f32_16x16x32_bf16(ax1[kk].v, bc[nt][kk], vac[1][nt], 0, 0, 0);
    }
  }

  // vp write (bf16)
  ushort_t* vo = (ushort_t*)(ws_c + OFF_VP) + ((size_t)(b * RCH + ch) * NCAP) * DIM;
  #pragma unroll
  for (int dt = 0; dt < 2; ++dt)
    #pragma unroll
    for (int nt = 0; nt < 2; ++nt) {
      int n = nt * 16 + lr;
      int d0 = wv * 32 + dt * 16 + q * 4;
      f32x4 v = vac[dt][nt];
      uint2 pk;
      pk.x = f2bf(v[0]) | (f2bf(v[1]) << 16);
      pk.y = f2bf(v[2]) | (f2bf(v[3]) << 16);
      *(uint2*)(vo + (size_t)n * DIM + d0) = pk;
    }

  // ---- tail election: 8th finisher for batch b reduces + squashes ----
  __syncthreads();                        // drain all threads' vp stores
  if (t == 0) {
    __threadfence();                      // release vp to device scope
    int* cnt = (int*)(ws_c + OFF_CNT) + (PASS - 1) * BATCH + b;
    int old = atomicAdd(cnt, 1);
    *(int*)(smem + CTOFF) = (old == RCH - 1);
  }
  __syncthreads();
  if (!*(int*)(smem + CTOFF)) return;
  __threadfence();                        // acquire other blocks' vp

  float* vinL = (float*)smem;             // [32][128] overlays dead X tile
  float* oshL = (float*)(smem + 16384);   // [512]
  const ushort_t* vpb = (const ushort_t*)(ws_c + OFF_VP) + (size_t)b * RCH * NCAP * DIM;
  for (int j = 0; j < 16; ++j) {
    int idx = j * 256 + t;
    float s = 0.f;
    for (int c = 0; c < RCH; ++c)
      s += bf2f(vpb[(size_t)c * NCAP * DIM + idx]);
    vinL[idx] = s;
  }
  __syncthreads();

  const float* wt = ws_c + OFF_WT;
  for (int g = 0; g < 2; ++g) {
    int k = g * 256 + t;
    const float4* vr = (const float4*)(vinL + (size_t)(k >> 4) * DIM);
    const float4* wtr = (const float4*)(wt + (size_t)k * DIM);
    float p = 0.f;
    #pragma unroll 8
    for (int i = 0; i < 32; ++i) {
      float4 wv2 = wtr[i], vv = vr[i];
      p += wv2.x * vv.x + wv2.y * vv.y + wv2.z * vv.z + wv2.w * vv.w;
    }
    float sq = p * p;
    sq += __shfl_xor(sq, 1, 16);
    sq += __shfl_xor(sq, 2, 16);
    sq += __shfl_xor(sq, 4, 16);
    sq += __shfl_xor(sq, 8, 16);
    sq += EPS_;
    float scale = sqrtf(sq) / (0.5f + sq);
    float o = scale * p;
    if (PASS == 2) outp[(size_t)b * KTOT + k] = o;
    else           oshL[k] = o;
  }

  if (PASS == 1) {
    __syncthreads();
    ushort_t* ub = (ushort_t*)(ws_c + OFF_UBF) + (size_t)b * NCAP * DIM;
    for (int j = 0; j < 16; ++j) {
      int idx = j * 256 + t;
      int n = idx >> 7, d = idx & 127;
      float a = 0.f;
      #pragma unroll
      for (int dc = 0; dc < DCAPS; ++dc)
        a += wt[(size_t)(n * DCAPS + dc) * DIM + d] * oshL[n * DCAPS + dc];
      ub[(size_t)n * DIM + d] = (ushort_t)f2bf(a);
    }
  }
}

extern "C" void kernel_launch(void* const* d_in, const int* in_sizes, int n_in,
                              void* d_out, int out_size, void* d_ws, size_t ws_size,
                              hipStream_t stream) {
  (void)in_sizes; (void)n_in; (void)out_size; (void)ws_size;
  const float* x = (const float*)d_in[0];
  const float* w = (const float*)d_in[1];   // kernel[0] : [128][512]
  float* out = (float*)d_out;
  float* ws  = (float*)d_ws;

  k_pre<<<dim3(8, BATCH + 1), 256, 0, stream>>>(x, w, ws);
  k_ou0<<<dim3(4, BATCH), 128, 0, stream>>>(ws);
  k_route<1><<<dim3(RCH, BATCH), 256, 0, stream>>>(ws, out);
  k_route<2><<<dim3(RCH, BATCH), 256, 0, stream>>>(ws, out);
}

// Round 11
// 70.816 us; speedup vs baseline: 4.1838x; 4.1838x over previous
//
#include <hip/hip_runtime.h>

#define BATCH 128
#define SEQ   1024
#define DIM   128
#define NCAP  32
#define DCAPS 16
#define KTOT  512
#define EPS_  1e-7f
#define RCH   8
#define RROWS 128

// ws layout (float offsets)
#define OFF_SPART 0                                  // [B][RCH][DIM] f32
#define OFF_WT    (OFF_SPART + BATCH*RCH*DIM)        // [KTOT][DIM] f32
#define OFF_UBF   (OFF_WT + KTOT*DIM)                // [B][NCAP][DIM] bf16
#define OFF_VP    (OFF_UBF + BATCH*NCAP*DIM/2)       // [B][RCH][NCAP][DIM] bf16
#define OFF_XROW  (OFF_VP + BATCH*RCH*NCAP*DIM/2)    // [B][SEQ][DIM] bf16
// end ≈ 43.8 MB

typedef __attribute__((ext_vector_type(8))) short short8v;   // 8 bf16
typedef __attribute__((ext_vector_type(4))) float f32x4;
typedef unsigned short ushort_t;

// subtiled LDS layout for the X tile: subtile (r4,d16) holds rows r4*4..+3,
// cols d16*16..+15, row-major [4][16] bf16 (32B row stride).
// stride 176 = 128B payload + 48B gap: disjoint; staging stores, phase-A
// ds_read_b128 and phase-C u16 gathers are all bank-balanced (q-group bases
// land at {0,96,64,32} mod 128 -> full 32-bank spread, 2 lanes/bank).
#define SUBOFF(r4, d16) (((r4)*8 + (d16))*176)
#define CTOFF 45056      // > max subtile end (255*176+128 = 45008), 128-aligned
#define SMEMSZ (CTOFF + 8192)

__device__ __forceinline__ unsigned f2bf(float f) {
  unsigned u = __float_as_uint(f);
  u += 0x7fffu + ((u >> 16) & 1u);    // RNE
  return u >> 16;
}
__device__ __forceinline__ float bf2f(ushort_t v) {
  return __uint_as_float(((unsigned)v) << 16);
}
__device__ __forceinline__ uint4 pack8(float4 a, float4 b) {
  uint4 r;
  r.x = f2bf(a.x) | (f2bf(a.y) << 16);
  r.y = f2bf(a.z) | (f2bf(a.w) << 16);
  r.z = f2bf(b.x) | (f2bf(b.y) << 16);
  r.w = f2bf(b.z) | (f2bf(b.w) << 16);
  return r;
}

// ---------- kernel 1: colsum partials + WT transpose + xrow bf16 image ----------
__global__ __launch_bounds__(256)
void k_pre(const float* __restrict__ x, const float* __restrict__ w,
           float* __restrict__ ws) {
  int t = threadIdx.x;
  __shared__ __align__(16) char smem[33792];

  if (blockIdx.y == BATCH) {              // 8 blocks: LDS-tiled W transpose
    float* wl = (float*)smem;             // [128][66] padded tile
    int k0 = blockIdx.x * 64;
    for (int it = 0; it < 32; ++it) {
      int f = it * 256 + t;
      int kk = f & 63, d = f >> 6;
      wl[d * 66 + kk] = w[d * KTOT + k0 + kk];
    }
    __syncthreads();
    float* wt = ws + OFF_WT;
    for (int it = 0; it < 32; ++it) {
      int f = it * 256 + t;
      int d = f & 127, kk = f >> 7;
      wt[(size_t)(k0 + kk) * DIM + d] = wl[d * 66 + kk];
    }
    return;
  }
  int b = blockIdx.y, ch = blockIdx.x;
  float4* red0 = (float4*)smem;            // [16][16]
  float4* red1 = (float4*)(smem + 4096);   // [16][16]

  const float4* X4 = (const float4*)(x + ((size_t)b * SEQ + (size_t)ch * RROWS) * DIM);
  ushort_t* xrow = (ushort_t*)(ws + OFF_XROW) + ((size_t)b * SEQ + (size_t)ch * RROWS) * DIM;

  int seg = t & 15, grp = t >> 4;
  float4 a0 = make_float4(0.f,0.f,0.f,0.f), a1 = make_float4(0.f,0.f,0.f,0.f);
  for (int it = 0; it < 8; ++it) {
    int r = it * 16 + grp;
    float4 v0 = X4[(size_t)r * 32 + seg * 2];
    float4 v1 = X4[(size_t)r * 32 + seg * 2 + 1];
    a0.x += v0.x; a0.y += v0.y; a0.z += v0.z; a0.w += v0.w;
    a1.x += v1.x; a1.y += v1.y; a1.z += v1.z; a1.w += v1.w;
    *(uint4*)(xrow + (size_t)r * DIM + seg * 8) = pack8(v0, v1);
  }
  red0[grp * 16 + seg] = a0;
  red1[grp * 16 + seg] = a1;
  __syncthreads();

  if (t < 128) {
    int sg = t >> 3, e = t & 7;
    float s = 0.f;
    for (int g = 0; g < 16; ++g) {
      const float* p0 = (const float*)&red0[g * 16 + sg];
      const float* p1 = (const float*)&red1[g * 16 + sg];
      s += (e < 4) ? p0[e] : p1[e - 4];
    }
    ws[OFF_SPART + ((size_t)b * RCH + ch) * DIM + t] = s;
  }
}

// ---------- kernel 2: squash + u(bf16) (or final output) ----------
template<int MODE>
__global__ __launch_bounds__(128)
void k_ou(float* __restrict__ ws, float* __restrict__ outp) {
  int b = blockIdx.y, bx = blockIdx.x, t = threadIdx.x;
  int k = bx * 128 + t;
  __shared__ float vin[8 * DIM];
  __shared__ float osh[128];

  if (MODE == 0) {
    const float* sp = ws + OFF_SPART + (size_t)b * RCH * DIM;
    float s = 0.f;
    for (int c = 0; c < RCH; ++c) s += sp[c * DIM + t];
    vin[t] = s * (1.0f / 32.0f);
  } else {
    const ushort_t* vpb = (const ushort_t*)(ws + OFF_VP)
        + (size_t)b * RCH * NCAP * DIM;
    for (int j = 0; j < 8; ++j) {
      int n = bx * 8 + j;
      float s = 0.f;
      for (int c = 0; c < RCH; ++c)
        s += bf2f(vpb[(size_t)c * NCAP * DIM + n * DIM + t]);
      vin[j * DIM + t] = s;
    }
  }
  __syncthreads();

  int nl = t >> 4;
  const float4* vr = (const float4*)((MODE == 0) ? vin : (vin + nl * DIM));
  const float4* wtr = (const float4*)(ws + OFF_WT + (size_t)k * DIM);
  float p = 0.f;
  #pragma unroll 8
  for (int i = 0; i < 32; ++i) {
    float4 wv = wtr[i], vv = vr[i];
    p += wv.x * vv.x + wv.y * vv.y + wv.z * vv.z + wv.w * vv.w;
  }

  float sq = p * p;
  sq += __shfl_xor(sq, 1, 16);
  sq += __shfl_xor(sq, 2, 16);
  sq += __shfl_xor(sq, 4, 16);
  sq += __shfl_xor(sq, 8, 16);
  sq += EPS_;
  float scale = sqrtf(sq) / (0.5f + sq);
  float o = scale * p;

  if (MODE == 2) { outp[(size_t)b * KTOT + k] = o; return; }

  osh[t] = o;
  __syncthreads();

  const float* wt = ws + OFF_WT;
  ushort_t* ubf = (ushort_t*)(ws + OFF_UBF) + (size_t)b * NCAP * DIM;
  for (int j = 0; j < 8; ++j) {
    int n = bx * 8 + j;
    float a = 0.f;
    #pragma unroll
    for (int dc = 0; dc < DCAPS; ++dc)
      a += wt[(size_t)(n * DCAPS + dc) * DIM + t] * osh[j * DCAPS + dc];
    ubf[(size_t)n * DIM + t] = (ushort_t)f2bf(a);
  }
}

// ---------- kernel 3: MFMA routing pass, single subtiled LDS tile ----------
// stage xrow -> LDS subtiled; phase A reads row-frags (ds_read_b128);
// phase-C column gathers HOISTED before softmax (depend only on X tile).
__global__ __launch_bounds__(256)
void k_route(float* __restrict__ ws_c) {
  __shared__ __align__(16) char smem[SMEMSZ];

  int b = blockIdx.y, ch = blockIdx.x, t = threadIdx.x;
  int wv = t >> 6;
  int l  = t & 63;
  int q  = l >> 4;
  int lr = l & 15;

  const ushort_t* ubf  = (const ushort_t*)(ws_c + OFF_UBF) + (size_t)b * NCAP * DIM;
  const ushort_t* xrow = (const ushort_t*)(ws_c + OFF_XROW) + ((size_t)b * SEQ + (size_t)ch * RROWS) * DIM;

  // ---- stage tile: global row-major -> LDS subtiled ----
  #pragma unroll
  for (int it = 0; it < 8; ++it) {
    int f = it * 256 + t;
    int r = f >> 4, d0 = (f & 15) * 8;
    uint4 v = *(const uint4*)(xrow + (size_t)r * DIM + d0);
    *(uint4*)(smem + SUBOFF(r >> 2, d0 >> 4) + (r & 3) * 32 + ((d0 & 15) << 1)) = v;
  }

  // phase A A-frags from global (tiny, L2-hot)
  short8v ufr[2][4];
  #pragma unroll
  for (int nt = 0; nt < 2; ++nt)
    #pragma unroll
    for (int kk = 0; kk < 4; ++kk)
      ufr[nt][kk] = *(const short8v*)(ubf + (size_t)(nt * 16 + lr) * DIM + kk * 32 + q * 8);

  __syncthreads();

  // ---- phase A: B-frags = X rows from LDS ----
  f32x4 acc[2][2];
  #pragma unroll
  for (int rt = 0; rt < 2; ++rt)
    #pragma unroll
    for (int nt = 0; nt < 2; ++nt)
      acc[rt][nt] = (f32x4){0.f, 0.f, 0.f, 0.f};

  #pragma unroll
  for (int kk = 0; kk < 4; ++kk) {
    #pragma unroll
    for (int rt = 0; rt < 2; ++rt) {
      int r = wv * 32 + rt * 16 + lr;
      short8v xf = *(const short8v*)(smem + SUBOFF(r >> 2, 2 * kk + (q >> 1))
                                     + (r & 3) * 32 + (q & 1) * 16);
      #pragma unroll
      for (int nt = 0; nt < 2; ++nt)
        acc[rt][nt] = __builtin_amdgcn_mfma_f32_16x16x32_bf16(
            ufr[nt][kk], xf, acc[rt][nt], 0, 0, 0);
    }
  }

  // ---- phase C A-frag column gathers (X tile only; hoisted pre-softmax
  //      so LDS issue/latency overlaps the softmax VALU work) ----
  union { short8v v; ushort_t s[8]; } ax0[4], ax1[4];
  #pragma unroll
  for (int kk = 0; kk < 4; ++kk) {
    #pragma unroll
    for (int e = 0; e < 8; ++e) {
      int r4 = kk * 8 + q * 2 + (e >> 2);
      int boff = (e & 3) * 32 + lr * 2;
      ax0[kk].s[e] = *(const ushort_t*)(smem + SUBOFF(r4, wv * 2    ) + boff);
      ax1[kk].s[e] = *(const ushort_t*)(smem + SUBOFF(r4, wv * 2 + 1) + boff);
    }
  }

  // ---- softmax over n; c -> ct (bf16, swizzled) ----
  #pragma unroll
  for (int rt = 0; rt < 2; ++rt) {
    float v[8];
    #pragma unroll
    for (int nt = 0; nt < 2; ++nt)
      #pragma unroll
      for (int j = 0; j < 4; ++j) v[nt * 4 + j] = acc[rt][nt][j];
    float m = v[0];
    #pragma unroll
    for (int i = 1; i < 8; ++i) m = fmaxf(m, v[i]);
    m = fmaxf(m, __shfl_xor(m, 16));
    m = fmaxf(m, __shfl_xor(m, 32));
    float e[8], s = 0.f;
    #pragma unroll
    for (int i = 0; i < 8; ++i) { e[i] = __expf(v[i] - m); s += e[i]; }
    s += __shfl_xor(s, 16);
    s += __shfl_xor(s, 32);
    float inv = 1.0f / s;
    int r = wv * 32 + rt * 16 + lr;
    int rs = r >> 3, rb = (r & 7) * 2;
    #pragma unroll
    for (int nt = 0; nt < 2; ++nt)
      #pragma unroll
      for (int j = 0; j < 4; ++j) {
        int n = nt * 16 + q * 4 + j;
        *(ushort_t*)(smem + CTOFF + n * 256 + ((rs ^ (n & 15)) << 4) + rb) =
            (ushort_t)f2bf(e[nt * 4 + j] * inv);
      }
  }

  __syncthreads();

  // ---- phase C: B-frags from ct; MFMAs ----
  short8v bc[2][4];
  #pragma unroll
  for (int nt = 0; nt < 2; ++nt) {
    int n2 = nt * 16 + lr;
    #pragma unroll
    for (int kk = 0; kk < 4; ++kk)
      bc[nt][kk] = *(const short8v*)(smem + CTOFF + n2 * 256 + (((4 * kk + q) ^ (n2 & 15)) << 4));
  }

  f32x4 vac[2][2];
  #pragma unroll
  for (int dt = 0; dt < 2; ++dt)
    #pragma unroll
    for (int nt = 0; nt < 2; ++nt)
      vac[dt][nt] = (f32x4){0.f, 0.f, 0.f, 0.f};

  #pragma unroll
  for (int kk = 0; kk < 4; ++kk) {
    #pragma unroll
    for (int nt = 0; nt < 2; ++nt) {
      vac[0][nt] = __builtin_amdgcn_mfma_f32_16x16x32_bf16(ax0[kk].v, bc[nt][kk], vac[0][nt], 0, 0, 0);
      vac[1][nt] = __builtin_amdgcn_mfma_f32_16x16x32_bf16(ax1[kk].v, bc[nt][kk], vac[1][nt], 0, 0, 0);
    }
  }

  // lane holds V^T[d = wv*32 + dt*16 + q*4 + j][n = nt*16 + lr]; write bf16
  ushort_t* vo = (ushort_t*)(ws_c + OFF_VP) + ((size_t)(b * RCH + ch) * NCAP) * DIM;
  #pragma unroll
  for (int dt = 0; dt < 2; ++dt)
    #pragma unroll
    for (int nt = 0; nt < 2; ++nt) {
      int n = nt * 16 + lr;
      int d0 = wv * 32 + dt * 16 + q * 4;
      f32x4 v = vac[dt][nt];
      uint2 pk;
      pk.x = f2bf(v[0]) | (f2bf(v[1]) << 16);
      pk.y = f2bf(v[2]) | (f2bf(v[3]) << 16);
      *(uint2*)(vo + (size_t)n * DIM + d0) = pk;
    }
}

extern "C" void kernel_launch(void* const* d_in, const int* in_sizes, int n_in,
                              void* d_out, int out_size, void* d_ws, size_t ws_size,
                              hipStream_t stream) {
  (void)in_sizes; (void)n_in; (void)out_size; (void)ws_size;
  const float* x = (const float*)d_in[0];
  const float* w = (const float*)d_in[1];   // kernel[0] : [128][512]
  float* out = (float*)d_out;
  float* ws  = (float*)d_ws;

  k_pre<<<dim3(8, BATCH + 1), 256, 0, stream>>>(x, w, ws);
  k_ou<0><<<dim3(4, BATCH), 128, 0, stream>>>(ws, out);
  k_route<<<dim3(RCH, BATCH), 256, 0, stream>>>(ws);
  k_ou<1><<<dim3(4, BATCH), 128, 0, stream>>>(ws, out);
  k_route<<<dim3(RCH, BATCH), 256, 0, stream>>>(ws);
  k_ou<2><<<dim3(4, BATCH), 128, 0, stream>>>(ws, out);
}